// Round 15
// baseline (284.592 us; speedup 1.0000x reference)
//
#include <hip/hip_runtime.h>
#include <cstdint>
#include <cstddef>

namespace {

constexpr int N_ITEMS = 10000;
constexpr int N_TAGS  = 2000;
constexpr int VOCAB   = 50000;
constexpr int KTAG    = 32;
constexpr int KITEM   = 8;
constexpr int HD      = 128;
constexpr int NLAYER  = 4;
constexpr int GWSZ = NLAYER * 131072;   // gate frag elems per etype (u16)
constexpr int EWSZ = NLAYER * 32768;    // epilogue frag elems per etype
constexpr int FWSZ = 16384;             // W_final frag elems
constexpr int NSCAN = (VOCAB + 1023) / 1024;   // 49

constexpr float L2E  = 1.4426950408889634f;
constexpr float TL2E = 2.8853900817779268f;

using bfrag = __attribute__((ext_vector_type(8))) short;
using f32x4 = __attribute__((ext_vector_type(4))) float;

__device__ __forceinline__ float exp2ft(float x) { return __builtin_amdgcn_exp2f(x); }

__device__ __forceinline__ uint16_t f2bf(float f) {
  uint32_t u = __float_as_uint(f);
  u += 0x7fffu + ((u >> 16) & 1u);   // RNE
  return (uint16_t)(u >> 16);
}

__device__ __forceinline__ uint32_t cvt_pk_bf16(float a, float b) {
  uint32_t d;
  asm("v_cvt_pk_bf16_f32 %0, %1, %2" : "=v"(d) : "v"(a), "v"(b));
  return d;
}

__global__ void zero_k(int* present, int* hists, int nh) {
  int i = blockIdx.x * blockDim.x + threadIdx.x;
  if (i < VOCAB) present[i] = 0;
  else if (i - VOCAB < nh) hists[i - VOCAB] = 0;
}

// mark presence + length histograms
__global__ void markhist_k(const int* __restrict__ items, int* __restrict__ present,
                           const int* __restrict__ len_tag, const int* __restrict__ len_item,
                           int* __restrict__ hist_tag, int* __restrict__ hist_item) {
  int i = blockIdx.x * blockDim.x + threadIdx.x;
  if (i < N_ITEMS) present[items[i]] = 1;
  if (i < N_TAGS) atomicAdd(&hist_tag[len_tag[i]], 1);
  int j = i - N_TAGS;
  if (j >= 0 && j < N_ITEMS) atomicAdd(&hist_item[len_item[j]], 1);
}

// per-1024-chunk sums; block 0 thread 0 also computes bucket bases
__global__ __launch_bounds__(256) void scanA_k(const int* __restrict__ present,
                                               int* __restrict__ partial,
                                               const int* __restrict__ hist_tag,
                                               int* __restrict__ base_tag,
                                               const int* __restrict__ hist_item,
                                               int* __restrict__ base_item) {
  __shared__ int ws[4];
  const int b = blockIdx.x, tid = threadIdx.x;
  const int base = b * 1024 + tid * 4;
  int s = 0;
  if (base < VOCAB) {
    int4 v = *reinterpret_cast<const int4*>(present + base);
    s = v.x + v.y + v.z + v.w;
  }
  const int lane = tid & 63, wv = tid >> 6;
  #pragma unroll
  for (int off = 32; off >= 1; off >>= 1) s += __shfl_down(s, off);
  if (lane == 0) ws[wv] = s;
  __syncthreads();
  if (tid == 0) partial[b] = ws[0] + ws[1] + ws[2] + ws[3];
  if (b == 0 && tid == 0) {
    int acc = 0;
    for (int l = KTAG; l >= 1; --l) { base_tag[l] = acc; acc += hist_tag[l]; }
    acc = 0;
    for (int l = KITEM; l >= 1; --l) { base_item[l] = acc; acc += hist_item[l]; }
  }
}

// final scan: each block redundantly wave-scans the 49 partials
__global__ __launch_bounds__(256) void scanC_k(const int* __restrict__ present,
                                               const int* __restrict__ partial,
                                               int* __restrict__ rank) {
  __shared__ int ws[4];
  __shared__ int pscan[64];
  const int b = blockIdx.x, tid = threadIdx.x;
  if (tid < 64) {
    int v = (tid < NSCAN) ? partial[tid] : 0;
    int sc = v;
    #pragma unroll
    for (int off = 1; off < 64; off <<= 1) {
      int u = __shfl_up(sc, off);
      if (tid >= off) sc += u;
    }
    pscan[tid] = sc;   // inclusive
  }
  const int base = b * 1024 + tid * 4;
  int4 v = {0, 0, 0, 0};
  if (base < VOCAB) v = *reinterpret_cast<const int4*>(present + base);
  const int s = v.x + v.y + v.z + v.w;
  const int lane = tid & 63, wv = tid >> 6;
  int sc = s;
  #pragma unroll
  for (int off = 1; off < 64; off <<= 1) {
    int u = __shfl_up(sc, off);
    if (lane >= off) sc += u;
  }
  if (lane == 63) ws[wv] = sc;
  __syncthreads();
  int woff = (b > 0) ? pscan[b - 1] : 0;
  for (int w = 0; w < wv; w++) woff += ws[w];
  const int excl = woff + sc - s;
  if (base < VOCAB) {
    int4 r;
    r.x = excl; r.y = excl + v.x; r.z = excl + v.x + v.y; r.w = excl + v.x + v.y + v.z;
    *reinterpret_cast<int4*>(rank + base) = r;
  }
  if (b == 0 && tid == 0) rank[VOCAB] = pscan[NSCAN - 1];
}

constexpr int NBPI  = VOCAB * 32 + N_ITEMS * 32 + N_TAGS * 32 + N_ITEMS;
constexpr int NCONV = 2 * GWSZ + 2 * EWSZ + FWSZ;

__global__ void prep_k(const int* __restrict__ present, const int* __restrict__ rank,
                       const int* __restrict__ items, const float* __restrict__ table,
                       const float* __restrict__ tagt,
                       uint16_t* __restrict__ hib, uint16_t* __restrict__ ttb,
                       int* __restrict__ inv,
                       const float* __restrict__ WihA, const float* __restrict__ WhhA,
                       const float* __restrict__ WihR, const float* __restrict__ WhhR,
                       const float* __restrict__ WsA,  const float* __restrict__ WnA,
                       const float* __restrict__ WsR,  const float* __restrict__ WnR,
                       const float* __restrict__ Wf,
                       uint16_t* __restrict__ GgA, uint16_t* __restrict__ GgR,
                       uint16_t* __restrict__ GeA, uint16_t* __restrict__ GeR,
                       uint16_t* __restrict__ GWf,
                       const int* __restrict__ len_tag, const int* __restrict__ len_item,
                       int* __restrict__ base_tag, int* __restrict__ base_item,
                       int* __restrict__ ord_tag, int* __restrict__ ord_item) {
  int gid = blockIdx.x * blockDim.x + threadIdx.x;
  if (gid < VOCAB * 32) {
    int v = gid >> 5, q = gid & 31;
    if (present[v]) {
      int slot = rank[v];
      float4 x = reinterpret_cast<const float4*>(table + (size_t)v * HD)[q];
      ushort4 u = make_ushort4(f2bf(x.x), f2bf(x.y), f2bf(x.z), f2bf(x.w));
      *reinterpret_cast<ushort4*>(hib + (size_t)slot * HD + q * 4) = u;
    }
  } else if (gid < VOCAB * 32 + N_ITEMS * 32) {
    int g = gid - VOCAB * 32;
    int slot = g >> 5, q = g & 31;
    if (slot >= rank[VOCAB]) {
      float4 x = reinterpret_cast<const float4*>(table)[q];
      ushort4 u = make_ushort4(f2bf(x.x), f2bf(x.y), f2bf(x.z), f2bf(x.w));
      *reinterpret_cast<ushort4*>(hib + (size_t)slot * HD + q * 4) = u;
    }
  } else if (gid < VOCAB * 32 + N_ITEMS * 32 + N_TAGS * 32) {
    int g = gid - VOCAB * 32 - N_ITEMS * 32;
    int tg = g >> 5, q = g & 31;
    float4 x = reinterpret_cast<const float4*>(tagt + (size_t)tg * HD)[q];
    ushort4 u = make_ushort4(f2bf(x.x), f2bf(x.y), f2bf(x.z), f2bf(x.w));
    *reinterpret_cast<ushort4*>(ttb + (size_t)tg * HD + q * 4) = u;
  } else if (gid < NBPI) {
    int i = gid - VOCAB * 32 - N_ITEMS * 32 - N_TAGS * 32;
    if (i < N_ITEMS) inv[i] = rank[items[i]];
  } else if (gid < NBPI + 2 * GWSZ) {
    int o = gid - NBPI;
    const bool A = (o < GWSZ);
    int oo = A ? o : o - GWSZ;
    const float* Wih = A ? WihA : WihR;
    const float* Whh = A ? WhhA : WhhR;
    uint16_t* outp = A ? GgA : GgR;
    int j = oo & 7, lane = (oo >> 3) & 63, s = (oo >> 9) & 7, g = (oo >> 12) & 3,
        w = (oo >> 14) & 7, l = oo >> 17;
    int k = s * 32 + ((lane >> 4) << 3) + j;
    int c = g * 128 + w * 16 + (lane & 15);
    float v = (k < 128) ? Wih[((size_t)l * 512 + c) * 128 + k]
                        : Whh[((size_t)l * 512 + c) * 128 + (k - 128)];
    v *= (g == 2) ? TL2E : -L2E;
    outp[oo] = f2bf(v);
  } else if (gid < NBPI + 2 * GWSZ + 2 * EWSZ) {
    int oe = gid - NBPI - 2 * GWSZ;
    const bool A = (oe < EWSZ);
    int oo = A ? oe : oe - EWSZ;
    const float* Ws = A ? WsA : WsR;
    const float* Wn = A ? WnA : WnR;
    uint16_t* outp = A ? GeA : GeR;
    int j = oo & 7, lane = (oo >> 3) & 63, s = (oo >> 9) & 7, w = (oo >> 12) & 7, l = oo >> 15;
    int k = s * 32 + ((lane >> 4) << 3) + j;
    int c = w * 16 + (lane & 15);
    float v = (k < 128) ? Ws[((size_t)l * 128 + c) * 128 + k]
                        : Wn[((size_t)l * 128 + c) * 128 + (k - 128)];
    outp[oo] = f2bf(v);
  } else if (gid < NBPI + NCONV) {
    int oo = gid - NBPI - 2 * GWSZ - 2 * EWSZ;
    int j = oo & 7, lane = (oo >> 3) & 63, s = (oo >> 9) & 3, w = oo >> 11;
    int k = s * 32 + ((lane >> 4) << 3) + j;
    int c = w * 16 + (lane & 15);
    GWf[oo] = f2bf(Wf[(size_t)c * 128 + k]);
  } else {
    int i = gid - NBPI - NCONV;
    if (i < N_TAGS) {
      int pos = atomicAdd(&base_tag[len_tag[i]], 1);
      ord_tag[pos] = i;
    }
    int j = i - N_TAGS;
    if (j >= 0 && j < N_ITEMS) {
      int pos = atomicAdd(&base_item[len_item[j]], 1);
      ord_item[pos] = j;
    }
  }
}

struct ConvArgs3 {
  const uint16_t* hsrc; const uint16_t* hdst;   // bf16 features
  const int* nbr; const int* len; const int* ord;
  const uint16_t* Wg;   // gate A-frags (pre-scaled), layer slice
  const uint16_t* We;   // epilogue A-frags, layer slice
  const float* bih; const float* bhh; const float* bvec;
  const float* gamma; const float* beta;
  uint16_t* outbf;
  int K; int Klog; int ln; int nblk;
};

// Block = 16 dst nodes, 8 waves. A = weights (reg-resident).
// x B-frags loaded DIRECT global->reg; only h exchange via LDS.
// hs is declared at 2x20480 u16 (81.9 KB) but indexed only in its low 4 KB:
// the array is genuinely used, so the full allocation cannot be DCE'd.
// Total static LDS ~85 KB > 160/2 KB -> hardware-guaranteed 1 block/CU:
// the 32-step tag chain owns its CU's MFMA pipes (no co-resident dilution).
__global__ __launch_bounds__(512, 2)
void layer11_k(ConvArgs3 targ, ConvArgs3 iarg) {
  const bool is_tag = ((int)blockIdx.x < targ.nblk);
  const ConvArgs3& a = is_tag ? targ : iarg;
  const int blk  = is_tag ? (int)blockIdx.x : ((int)blockIdx.x - targ.nblk);
  const int tid  = threadIdx.x;
  const int wv   = tid >> 6;
  const int lane = tid & 63;
  const int n0   = blk * 16;
  const int K    = a.K;
  const int Klog = a.Klog;

  __shared__ __align__(16) uint16_t hs[2][20480];   // occupancy throttle (used array)
  __shared__ int nbr_s[16 * KTAG];
  __shared__ float2 red[8][16];
  __shared__ int ids_s[16], lens_s[16];

  if (tid < 16) {
    int id = a.ord[n0 + tid];
    ids_s[tid]  = id;
    lens_s[tid] = a.len[id];
  }
  *reinterpret_cast<ushort4*>(&hs[0][tid * 4]) = make_ushort4(0, 0, 0, 0);
  __syncthreads();

  // stage neighbor lists (16 nodes x K ints)
  for (int i = tid; i < (16 << Klog); i += 512)
    nbr_s[i] = a.nbr[(size_t)ids_s[i >> Klog] * K + (i & (K - 1))];

  const int n  = lane & 15;                 // node column
  const int dq = lane >> 4;                 // k-quarter (B) / dim-quarter (D)
  const int d0 = wv * 16 + dq * 4;
  const int lenN = lens_s[n];
  const int kq = dq * 8;                    // this lane's k-offset within 32-slice

  int tmax = 1;
  #pragma unroll
  for (int b = 0; b < 16; b++) tmax = max(tmax, lens_s[b]);

  int offs[4];
  #pragma unroll
  for (int s = 0; s < 4; s++)
    offs[s] = (n * 128 + s * 32 + kq) ^ ((n & 7) << 3);
  const int hwo = (n * 128 + d0) ^ ((n & 7) << 3);

  bfrag Ag[4][8];
  #pragma unroll
  for (int g = 0; g < 4; g++) {
    #pragma unroll
    for (int s = 0; s < 8; s++)
      Ag[g][s] = *reinterpret_cast<const bfrag*>(
          a.Wg + (size_t)((((wv * 4 + g) * 8 + s) * 64 + lane) * 8));
  }

  f32x4 bias4[4];
  #pragma unroll
  for (int g = 0; g < 4; g++) {
    f32x4 bi = *reinterpret_cast<const f32x4*>(a.bih + g * 128 + d0);
    f32x4 bh = *reinterpret_cast<const f32x4*>(a.bhh + g * 128 + d0);
    const float sc = (g == 2) ? TL2E : -L2E;
    bias4[g] = (bi + bh) * sc;
  }

  __syncthreads();   // nbr_s + hs-zero visible

  // x B-frags for t=0, direct from global (lane reads node n's neighbor row)
  bfrag Bx[4];
  {
    const int idx = nbr_s[n << Klog];
    const uint16_t* src = a.hsrc + (size_t)idx * HD + kq;
    #pragma unroll
    for (int s = 0; s < 4; s++)
      Bx[s] = *reinterpret_cast<const bfrag*>(src + s * 32);
  }

  float cst[4] = {0.f, 0.f, 0.f, 0.f};
  uint2 hpk = {0u, 0u};

  for (int t = 0; t < tmax; ++t) {
    const int cur = t & 1, nxt = cur ^ 1;

    f32x4 C[4];
    #pragma unroll
    for (int g = 0; g < 4; g++) C[g] = bias4[g];

    // x-part: consume Bx (registers, no LDS)
    #pragma unroll
    for (int s = 0; s < 4; s++) {
      #pragma unroll
      for (int g = 0; g < 4; g++)
        C[g] = __builtin_amdgcn_mfma_f32_16x16x32_bf16(Ag[g][s], Bx[s], C[g], 0, 0, 0);
    }

    // reload Bx for t+1 (WAR after consumption; a full step of latency slack)
    {
      const int tn = (t + 1 < K) ? t + 1 : K - 1;
      const int idx = nbr_s[(n << Klog) + tn];
      const uint16_t* src = a.hsrc + (size_t)idx * HD + kq;
      #pragma unroll
      for (int s = 0; s < 4; s++)
        Bx[s] = *reinterpret_cast<const bfrag*>(src + s * 32);
    }

    // h-part: LDS exchange (the only cross-wave dependency)
    #pragma unroll
    for (int s = 0; s < 4; s++) {
      bfrag bh = *reinterpret_cast<const bfrag*>(&hs[cur][offs[s]]);
      #pragma unroll
      for (int g = 0; g < 4; g++)
        C[g] = __builtin_amdgcn_mfma_f32_16x16x32_bf16(Ag[g][s + 4], bh, C[g], 0, 0, 0);
    }

    if (t < lenN) {
      float hv[4];
      #pragma unroll
      for (int r = 0; r < 4; r++) {
        const float iv = __builtin_amdgcn_rcpf(1.0f + exp2ft(C[0][r]));
        const float fv = __builtin_amdgcn_rcpf(1.0f + exp2ft(C[1][r]));
        const float gv = 1.0f - 2.0f * __builtin_amdgcn_rcpf(1.0f + exp2ft(C[2][r]));
        const float ov = __builtin_amdgcn_rcpf(1.0f + exp2ft(C[3][r]));
        const float cn = fmaf(fv, cst[r], iv * gv);
        cst[r] = cn;
        const float th = 1.0f - 2.0f * __builtin_amdgcn_rcpf(1.0f + exp2ft(cn * TL2E));
        hv[r] = ov * th;
      }
      hpk.x = cvt_pk_bf16(hv[0], hv[1]);
      hpk.y = cvt_pk_bf16(hv[2], hv[3]);
    }

    *reinterpret_cast<uint2*>(&hs[nxt][hwo]) = hpk;
    __syncthreads();
  }

  const int fin = tmax & 1;

  // ---- epilogue: out = hdst@Wself^T + hn@Wneigh^T + b (+LN for items) ----
  bfrag Ae[8];
  #pragma unroll
  for (int s = 0; s < 8; s++)
    Ae[s] = *reinterpret_cast<const bfrag*>(
        a.We + (size_t)(((wv * 8 + s) * 64 + lane) * 8));

  // hdst B-frags direct from global
  bfrag Bd[4];
  {
    const uint16_t* src = a.hdst + (size_t)ids_s[n] * HD + kq;
    #pragma unroll
    for (int s = 0; s < 4; s++)
      Bd[s] = *reinterpret_cast<const bfrag*>(src + s * 32);
  }

  f32x4 O = *reinterpret_cast<const f32x4*>(a.bvec + d0);
  #pragma unroll
  for (int s = 0; s < 4; s++)
    O = __builtin_amdgcn_mfma_f32_16x16x32_bf16(Ae[s], Bd[s], O, 0, 0, 0);
  #pragma unroll
  for (int s = 0; s < 4; s++) {
    bfrag bh = *reinterpret_cast<const bfrag*>(&hs[fin][offs[s]]);
    O = __builtin_amdgcn_mfma_f32_16x16x32_bf16(Ae[s + 4], bh, O, 0, 0, 0);
  }

  const int oid = ids_s[n];
  if (!a.ln) {
    uint2 pk;
    pk.x = cvt_pk_bf16(O[0], O[1]);
    pk.y = cvt_pk_bf16(O[2], O[3]);
    *reinterpret_cast<uint2*>(a.outbf + (size_t)oid * HD + d0) = pk;
  } else {
    float s1 = O[0] + O[1] + O[2] + O[3];
    float s2 = O[0] * O[0] + O[1] * O[1] + O[2] * O[2] + O[3] * O[3];
    s1 += __shfl_xor(s1, 16); s2 += __shfl_xor(s2, 16);
    s1 += __shfl_xor(s1, 32); s2 += __shfl_xor(s2, 32);
    if (dq == 0) red[wv][n] = make_float2(s1, s2);
    __syncthreads();
    float m1 = 0.f, m2 = 0.f;
    #pragma unroll
    for (int w = 0; w < 8; w++) {
      float2 v = red[w][n];
      m1 += v.x; m2 += v.y;
    }
    const float mu   = m1 * (1.f / 128.f);
    const float var  = m2 * (1.f / 128.f) - mu * mu;
    const float istd = rsqrtf(var + 1e-5f);
    f32x4 gm = *reinterpret_cast<const f32x4*>(a.gamma + d0);
    f32x4 bt = *reinterpret_cast<const f32x4*>(a.beta + d0);
    float v[4];
    #pragma unroll
    for (int r = 0; r < 4; r++)
      v[r] = (O[r] - mu) * istd * gm[r] + bt[r];
    uint2 pk;
    pk.x = cvt_pk_bf16(v[0], v[1]);
    pk.y = cvt_pk_bf16(v[2], v[3]);
    *reinterpret_cast<uint2*>(a.outbf + (size_t)oid * HD + d0) = pk;
  }
}

// final Linear (no bias) + LeakyReLU, gathered by inv. Block = 16 outputs.
__global__ __launch_bounds__(512)
void final2_k(const uint16_t* __restrict__ hib, const int* __restrict__ inv,
              const uint16_t* __restrict__ fWf, float* __restrict__ out) {
  __shared__ int rid[16];
  const int tid = threadIdx.x, wv = tid >> 6, lane = tid & 63;
  const int i0 = blockIdx.x * 16;
  if (tid < 16) rid[tid] = inv[i0 + tid];
  __syncthreads();

  const int n = lane & 15, dq = lane >> 4;
  const int d0 = wv * 16 + dq * 4;
  bfrag Af[4];
  #pragma unroll
  for (int s = 0; s < 4; s++)
    Af[s] = *reinterpret_cast<const bfrag*>(fWf + (size_t)(((wv * 4 + s) * 64 + lane) * 8));

  bfrag Br[4];
  {
    const uint16_t* src = hib + (size_t)rid[n] * HD + dq * 8;
    #pragma unroll
    for (int s = 0; s < 4; s++)
      Br[s] = *reinterpret_cast<const bfrag*>(src + s * 32);
  }

  f32x4 O = {0.f, 0.f, 0.f, 0.f};
  #pragma unroll
  for (int s = 0; s < 4; s++)
    O = __builtin_amdgcn_mfma_f32_16x16x32_bf16(Af[s], Br[s], O, 0, 0, 0);
  float4 res;
  res.x = (O[0] > 0.f) ? O[0] : 0.01f * O[0];
  res.y = (O[1] > 0.f) ? O[1] : 0.01f * O[1];
  res.z = (O[2] > 0.f) ? O[2] : 0.01f * O[2];
  res.w = (O[3] > 0.f) ? O[3] : 0.01f * O[3];
  *reinterpret_cast<float4*>(out + (size_t)(i0 + n) * HD + d0) = res;
}

} // namespace

extern "C" void kernel_launch(void* const* d_in, const int* in_sizes, int n_in,
                              void* d_out, int out_size, void* d_ws, size_t ws_size,
                              hipStream_t stream) {
  (void)in_sizes; (void)n_in; (void)out_size; (void)ws_size;

  const int*   items      = (const int*)d_in[0];
  const int*   nbr_item   = (const int*)d_in[1];
  const int*   len_tag    = (const int*)d_in[2];
  const int*   nbr_tag    = (const int*)d_in[3];
  const int*   len_item   = (const int*)d_in[4];
  const float* item_table = (const float*)d_in[5];
  const float* tag_table  = (const float*)d_in[6];
  const float* Wih_as   = (const float*)d_in[7];
  const float* Whh_as   = (const float*)d_in[8];
  const float* bih_as   = (const float*)d_in[9];
  const float* bhh_as   = (const float*)d_in[10];
  const float* Wself_as  = (const float*)d_in[11];
  const float* Wneigh_as = (const float*)d_in[12];
  const float* b_as      = (const float*)d_in[13];
  const float* Wih_ras   = (const float*)d_in[14];
  const float* Whh_ras   = (const float*)d_in[15];
  const float* bih_ras   = (const float*)d_in[16];
  const float* bhh_ras   = (const float*)d_in[17];
  const float* Wself_ras  = (const float*)d_in[18];
  const float* Wneigh_ras = (const float*)d_in[19];
  const float* b_ras      = (const float*)d_in[20];
  const float* ln_gamma = (const float*)d_in[21];
  const float* ln_beta  = (const float*)d_in[22];
  const float* W_final  = (const float*)d_in[23];
  float* out = (float*)d_out;

  char* p = (char*)d_ws;
  auto take = [&](size_t bytes) -> char* {
    char* r = p;
    p += (bytes + 255) & ~(size_t)255;
    return r;
  };
  int* present = (int*)take((size_t)VOCAB * sizeof(int));
  int* rank    = (int*)take((size_t)(VOCAB + 1) * sizeof(int));
  int* invp    = (int*)take((size_t)N_ITEMS * sizeof(int));
  int* partial = (int*)take(64 * sizeof(int));
  uint16_t* hti0 = (uint16_t*)take((size_t)N_ITEMS * HD * 2);
  uint16_t* htiA = (uint16_t*)take((size_t)N_ITEMS * HD * 2);
  uint16_t* htiB = (uint16_t*)take((size_t)N_ITEMS * HD * 2);
  uint16_t* htt0 = (uint16_t*)take((size_t)N_TAGS * HD * 2);
  uint16_t* httA = (uint16_t*)take((size_t)N_TAGS * HD * 2);
  uint16_t* httB = (uint16_t*)take((size_t)N_TAGS * HD * 2);
  uint16_t* WgA = (uint16_t*)take((size_t)GWSZ * 2);
  uint16_t* WgR = (uint16_t*)take((size_t)GWSZ * 2);
  uint16_t* WeA = (uint16_t*)take((size_t)EWSZ * 2);
  uint16_t* WeR = (uint16_t*)take((size_t)EWSZ * 2);
  uint16_t* fWf = (uint16_t*)take((size_t)FWSZ * 2);
  int* hists = (int*)take((size_t)(KTAG + 1 + KITEM + 1) * sizeof(int));
  int* hist_tag  = hists;
  int* hist_item = hists + KTAG + 1;
  int* base_tag  = (int*)take((size_t)(KTAG + 1) * sizeof(int));
  int* base_item = (int*)take((size_t)(KITEM + 1) * sizeof(int));
  int* ord_tag   = (int*)take((size_t)N_TAGS * sizeof(int));
  int* ord_item  = (int*)take((size_t)N_ITEMS * sizeof(int));

  const int NHIST = KTAG + 1 + KITEM + 1;
  const int NPREP = NBPI + NCONV + N_TAGS + N_ITEMS;

  zero_k<<<(VOCAB + NHIST + 255) / 256, 256, 0, stream>>>(present, hists, NHIST);
  markhist_k<<<(N_TAGS + N_ITEMS + 255) / 256, 256, 0, stream>>>(
      items, present, len_tag, len_item, hist_tag, hist_item);
  scanA_k<<<NSCAN, 256, 0, stream>>>(present, partial, hist_tag, base_tag,
                                     hist_item, base_item);
  scanC_k<<<NSCAN, 256, 0, stream>>>(present, partial, rank);
  prep_k<<<(NPREP + 255) / 256, 256, 0, stream>>>(
      present, rank, items, item_table, tag_table, hti0, htt0, invp,
      Wih_as, Whh_as, Wih_ras, Whh_ras, Wself_as, Wneigh_as, Wself_ras, Wneigh_ras,
      W_final, WgA, WgR, WeA, WeR, fWf,
      len_tag, len_item, base_tag, base_item, ord_tag, ord_item);

  const uint16_t* hi_cur = hti0; uint16_t* hi_nxt = htiA;
  const uint16_t* ht_cur = htt0; uint16_t* ht_nxt = httA;

  for (int l = 0; l < NLAYER; ++l) {
    ConvArgs3 ta, ia;
    ta.hsrc = hi_cur; ta.hdst = ht_cur;
    ta.nbr = nbr_item; ta.len = len_tag; ta.ord = ord_tag;
    ta.Wg = WgA + (size_t)l * 131072; ta.We = WeA + (size_t)l * 32768;
    ta.bih = bih_as + (size_t)l * 512; ta.bhh = bhh_as + (size_t)l * 512;
    ta.bvec = b_as + (size_t)l * HD;
    ta.gamma = nullptr; ta.beta = nullptr;
    ta.outbf = ht_nxt; ta.K = KTAG; ta.Klog = 5; ta.ln = 0; ta.nblk = N_TAGS / 16;

    ia.hsrc = ht_cur; ia.hdst = hi_cur;
    ia.nbr = nbr_tag; ia.len = len_item; ia.ord = ord_item;
    ia.Wg = WgR + (size_t)l * 131072; ia.We = WeR + (size_t)l * 32768;
    ia.bih = bih_ras + (size_t)l * 512; ia.bhh = bhh_ras + (size_t)l * 512;
    ia.bvec = b_ras + (size_t)l * HD;
    ia.gamma = ln_gamma + (size_t)l * HD; ia.beta = ln_beta + (size_t)l * HD;
    ia.outbf = hi_nxt; ia.K = KITEM; ia.Klog = 3; ia.ln = 1; ia.nblk = N_ITEMS / 16;

    layer11_k<<<ta.nblk + ia.nblk, 512, 0, stream>>>(ta, ia);

    hi_cur = hi_nxt; hi_nxt = (hi_cur == htiA) ? htiB : htiA;
    ht_cur = ht_nxt; ht_nxt = (ht_cur == httA) ? httB : httA;
  }

  final2_k<<<N_ITEMS / 16, 512, 0, stream>>>(hi_cur, invp, fWf, out);
}

// Round 16
// 209.162 us; speedup vs baseline: 1.3606x; 1.3606x over previous
//
#include <hip/hip_runtime.h>
#include <cstdint>
#include <cstddef>

namespace {

constexpr int N_ITEMS = 10000;
constexpr int N_TAGS  = 2000;
constexpr int VOCAB   = 50000;
constexpr int KTAG    = 32;
constexpr int KITEM   = 8;
constexpr int HD      = 128;
constexpr int NLAYER  = 4;
constexpr int GWSZ = NLAYER * 131072;   // gate frag elems per etype (u16)
constexpr int EWSZ = NLAYER * 32768;    // epilogue frag elems per etype
constexpr int FWSZ = 16384;             // W_final frag elems
constexpr int NSCAN = (VOCAB + 1023) / 1024;   // 49

constexpr float L2E  = 1.4426950408889634f;
constexpr float TL2E = 2.8853900817779268f;

using bfrag = __attribute__((ext_vector_type(8))) short;
using f32x4 = __attribute__((ext_vector_type(4))) float;

__device__ __forceinline__ float exp2ft(float x) { return __builtin_amdgcn_exp2f(x); }

__device__ __forceinline__ uint16_t f2bf(float f) {
  uint32_t u = __float_as_uint(f);
  u += 0x7fffu + ((u >> 16) & 1u);   // RNE
  return (uint16_t)(u >> 16);
}

__device__ __forceinline__ uint32_t cvt_pk_bf16(float a, float b) {
  uint32_t d;
  asm("v_cvt_pk_bf16_f32 %0, %1, %2" : "=v"(d) : "v"(a), "v"(b));
  return d;
}

__global__ void zero_k(int* present, int* hists, int nh) {
  int i = blockIdx.x * blockDim.x + threadIdx.x;
  if (i < VOCAB) present[i] = 0;
  else if (i - VOCAB < nh) hists[i - VOCAB] = 0;
}

// mark presence + length histograms via per-block LDS bins (kills the
// 12000-atomics-on-8-addresses L2 serialization; <=41 global atomics/block)
__global__ __launch_bounds__(256)
void markhist2_k(const int* __restrict__ items, int* __restrict__ present,
                 const int* __restrict__ len_tag, const int* __restrict__ len_item,
                 int* __restrict__ hist_tag, int* __restrict__ hist_item) {
  __shared__ int lh[48];   // [0..32] tag bins, [33+1..33+8] item bins
  const int tid = threadIdx.x;
  if (tid < 48) lh[tid] = 0;
  __syncthreads();
  const int i = blockIdx.x * 256 + tid;
  if (i < N_ITEMS) present[items[i]] = 1;
  if (i < N_TAGS)  atomicAdd(&lh[len_tag[i]], 1);
  if (i < N_ITEMS) atomicAdd(&lh[33 + len_item[i]], 1);
  __syncthreads();
  if (tid <= KTAG && lh[tid]) atomicAdd(&hist_tag[tid], lh[tid]);
  if (tid >= 34 && tid <= 33 + KITEM && lh[tid]) atomicAdd(&hist_item[tid - 33], lh[tid]);
}

// per-1024-chunk sums; block 0 thread 0 also computes bucket bases
__global__ __launch_bounds__(256) void scanA_k(const int* __restrict__ present,
                                               int* __restrict__ partial,
                                               const int* __restrict__ hist_tag,
                                               int* __restrict__ base_tag,
                                               const int* __restrict__ hist_item,
                                               int* __restrict__ base_item) {
  __shared__ int ws[4];
  const int b = blockIdx.x, tid = threadIdx.x;
  const int base = b * 1024 + tid * 4;
  int s = 0;
  if (base < VOCAB) {
    int4 v = *reinterpret_cast<const int4*>(present + base);
    s = v.x + v.y + v.z + v.w;
  }
  const int lane = tid & 63, wv = tid >> 6;
  #pragma unroll
  for (int off = 32; off >= 1; off >>= 1) s += __shfl_down(s, off);
  if (lane == 0) ws[wv] = s;
  __syncthreads();
  if (tid == 0) partial[b] = ws[0] + ws[1] + ws[2] + ws[3];
  if (b == 0 && tid == 0) {
    int acc = 0;
    for (int l = KTAG; l >= 1; --l) { base_tag[l] = acc; acc += hist_tag[l]; }
    acc = 0;
    for (int l = KITEM; l >= 1; --l) { base_item[l] = acc; acc += hist_item[l]; }
  }
}

// final scan: each block redundantly wave-scans the 49 partials
__global__ __launch_bounds__(256) void scanC_k(const int* __restrict__ present,
                                               const int* __restrict__ partial,
                                               int* __restrict__ rank) {
  __shared__ int ws[4];
  __shared__ int pscan[64];
  const int b = blockIdx.x, tid = threadIdx.x;
  if (tid < 64) {
    int v = (tid < NSCAN) ? partial[tid] : 0;
    int sc = v;
    #pragma unroll
    for (int off = 1; off < 64; off <<= 1) {
      int u = __shfl_up(sc, off);
      if (tid >= off) sc += u;
    }
    pscan[tid] = sc;   // inclusive
  }
  const int base = b * 1024 + tid * 4;
  int4 v = {0, 0, 0, 0};
  if (base < VOCAB) v = *reinterpret_cast<const int4*>(present + base);
  const int s = v.x + v.y + v.z + v.w;
  const int lane = tid & 63, wv = tid >> 6;
  int sc = s;
  #pragma unroll
  for (int off = 1; off < 64; off <<= 1) {
    int u = __shfl_up(sc, off);
    if (lane >= off) sc += u;
  }
  if (lane == 63) ws[wv] = sc;
  __syncthreads();
  int woff = (b > 0) ? pscan[b - 1] : 0;
  for (int w = 0; w < wv; w++) woff += ws[w];
  const int excl = woff + sc - s;
  if (base < VOCAB) {
    int4 r;
    r.x = excl; r.y = excl + v.x; r.z = excl + v.x + v.y; r.w = excl + v.x + v.y + v.z;
    *reinterpret_cast<int4*>(rank + base) = r;
  }
  if (b == 0 && tid == 0) rank[VOCAB] = pscan[NSCAN - 1];
}

// block-reserved counting-sort scatter: LDS local ranks + one global
// atomicAdd per bin per block (order within a bin is arbitrary; per-node
// outputs are independent of block grouping, so results are unchanged)
__global__ __launch_bounds__(256)
void scatter2_k(const int* __restrict__ len_tag, const int* __restrict__ len_item,
                int* __restrict__ base_tag, int* __restrict__ base_item,
                int* __restrict__ ord_tag, int* __restrict__ ord_item) {
  __shared__ int lh[48];
  __shared__ int lbase[48];
  const int tid = threadIdx.x;
  if (tid < 48) lh[tid] = 0;
  __syncthreads();
  const int i = blockIdx.x * 256 + tid;
  const int ltag  = (i < N_TAGS)  ? len_tag[i]  : -1;
  const int litem = (i < N_ITEMS) ? len_item[i] : -1;
  int rtag = 0, ritem = 0;
  if (ltag >= 0)  rtag  = atomicAdd(&lh[ltag], 1);
  if (litem >= 0) ritem = atomicAdd(&lh[33 + litem], 1);
  __syncthreads();
  if (tid <= KTAG && lh[tid]) lbase[tid] = atomicAdd(&base_tag[tid], lh[tid]);
  if (tid >= 34 && tid <= 33 + KITEM && lh[tid])
    lbase[tid] = atomicAdd(&base_item[tid - 33], lh[tid]);
  __syncthreads();
  if (ltag >= 0)  ord_tag[lbase[ltag] + rtag] = i;
  if (litem >= 0) ord_item[lbase[33 + litem] + ritem] = i;
}

constexpr int NBPI  = VOCAB * 32 + N_ITEMS * 32 + N_TAGS * 32 + N_ITEMS;
constexpr int NCONV = 2 * GWSZ + 2 * EWSZ + FWSZ;

__global__ void prep_k(const int* __restrict__ present, const int* __restrict__ rank,
                       const int* __restrict__ items, const float* __restrict__ table,
                       const float* __restrict__ tagt,
                       uint16_t* __restrict__ hib, uint16_t* __restrict__ ttb,
                       int* __restrict__ inv,
                       const float* __restrict__ WihA, const float* __restrict__ WhhA,
                       const float* __restrict__ WihR, const float* __restrict__ WhhR,
                       const float* __restrict__ WsA,  const float* __restrict__ WnA,
                       const float* __restrict__ WsR,  const float* __restrict__ WnR,
                       const float* __restrict__ Wf,
                       uint16_t* __restrict__ GgA, uint16_t* __restrict__ GgR,
                       uint16_t* __restrict__ GeA, uint16_t* __restrict__ GeR,
                       uint16_t* __restrict__ GWf) {
  int gid = blockIdx.x * blockDim.x + threadIdx.x;
  if (gid < VOCAB * 32) {
    int v = gid >> 5, q = gid & 31;
    if (present[v]) {
      int slot = rank[v];
      float4 x = reinterpret_cast<const float4*>(table + (size_t)v * HD)[q];
      ushort4 u = make_ushort4(f2bf(x.x), f2bf(x.y), f2bf(x.z), f2bf(x.w));
      *reinterpret_cast<ushort4*>(hib + (size_t)slot * HD + q * 4) = u;
    }
  } else if (gid < VOCAB * 32 + N_ITEMS * 32) {
    int g = gid - VOCAB * 32;
    int slot = g >> 5, q = g & 31;
    if (slot >= rank[VOCAB]) {
      float4 x = reinterpret_cast<const float4*>(table)[q];
      ushort4 u = make_ushort4(f2bf(x.x), f2bf(x.y), f2bf(x.z), f2bf(x.w));
      *reinterpret_cast<ushort4*>(hib + (size_t)slot * HD + q * 4) = u;
    }
  } else if (gid < VOCAB * 32 + N_ITEMS * 32 + N_TAGS * 32) {
    int g = gid - VOCAB * 32 - N_ITEMS * 32;
    int tg = g >> 5, q = g & 31;
    float4 x = reinterpret_cast<const float4*>(tagt + (size_t)tg * HD)[q];
    ushort4 u = make_ushort4(f2bf(x.x), f2bf(x.y), f2bf(x.z), f2bf(x.w));
    *reinterpret_cast<ushort4*>(ttb + (size_t)tg * HD + q * 4) = u;
  } else if (gid < NBPI) {
    int i = gid - VOCAB * 32 - N_ITEMS * 32 - N_TAGS * 32;
    if (i < N_ITEMS) inv[i] = rank[items[i]];
  } else if (gid < NBPI + 2 * GWSZ) {
    int o = gid - NBPI;
    const bool A = (o < GWSZ);
    int oo = A ? o : o - GWSZ;
    const float* Wih = A ? WihA : WihR;
    const float* Whh = A ? WhhA : WhhR;
    uint16_t* outp = A ? GgA : GgR;
    int j = oo & 7, lane = (oo >> 3) & 63, s = (oo >> 9) & 7, g = (oo >> 12) & 3,
        w = (oo >> 14) & 7, l = oo >> 17;
    int k = s * 32 + ((lane >> 4) << 3) + j;
    int c = g * 128 + w * 16 + (lane & 15);
    float v = (k < 128) ? Wih[((size_t)l * 512 + c) * 128 + k]
                        : Whh[((size_t)l * 512 + c) * 128 + (k - 128)];
    v *= (g == 2) ? TL2E : -L2E;
    outp[oo] = f2bf(v);
  } else if (gid < NBPI + 2 * GWSZ + 2 * EWSZ) {
    int oe = gid - NBPI - 2 * GWSZ;
    const bool A = (oe < EWSZ);
    int oo = A ? oe : oe - EWSZ;
    const float* Ws = A ? WsA : WsR;
    const float* Wn = A ? WnA : WnR;
    uint16_t* outp = A ? GeA : GeR;
    int j = oo & 7, lane = (oo >> 3) & 63, s = (oo >> 9) & 7, w = (oo >> 12) & 7, l = oo >> 15;
    int k = s * 32 + ((lane >> 4) << 3) + j;
    int c = w * 16 + (lane & 15);
    float v = (k < 128) ? Ws[((size_t)l * 128 + c) * 128 + k]
                        : Wn[((size_t)l * 128 + c) * 128 + (k - 128)];
    outp[oo] = f2bf(v);
  } else if (gid < NBPI + NCONV) {
    int oo = gid - NBPI - 2 * GWSZ - 2 * EWSZ;
    int j = oo & 7, lane = (oo >> 3) & 63, s = (oo >> 9) & 3, w = oo >> 11;
    int k = s * 32 + ((lane >> 4) << 3) + j;
    int c = w * 16 + (lane & 15);
    GWf[oo] = f2bf(Wf[(size_t)c * 128 + k]);
  }
}

struct ConvArgs3 {
  const uint16_t* hsrc; const uint16_t* hdst;   // bf16 features
  const int* nbr; const int* len; const int* ord;
  const uint16_t* Wg;   // gate A-frags (pre-scaled), layer slice
  const uint16_t* We;   // epilogue A-frags, layer slice
  const float* bih; const float* bhh; const float* bvec;
  const float* gamma; const float* beta;
  uint16_t* outbf;
  int K; int Klog; int ln; int nblk;
};

// Block = 16 dst nodes, 8 waves. A = weights (reg-resident).
// x B-frags loaded DIRECT global->reg; only h exchange via LDS.
// (Proven-floor R9 structure: T_step invariant to prefetch/barrier/priority/
// chain/occupancy across R7-R15 experiments.)
__global__ __launch_bounds__(512, 2)
void layer12_k(ConvArgs3 targ, ConvArgs3 iarg) {
  const bool is_tag = ((int)blockIdx.x < targ.nblk);
  const ConvArgs3& a = is_tag ? targ : iarg;
  const int blk  = is_tag ? (int)blockIdx.x : ((int)blockIdx.x - targ.nblk);
  const int tid  = threadIdx.x;
  const int wv   = tid >> 6;
  const int lane = tid & 63;
  const int n0   = blk * 16;
  const int K    = a.K;
  const int Klog = a.Klog;

  __shared__ __align__(16) uint16_t hs[2][2048];
  __shared__ int nbr_s[16 * KTAG];
  __shared__ float2 red[8][16];
  __shared__ int ids_s[16], lens_s[16];

  if (tid < 16) {
    int id = a.ord[n0 + tid];
    ids_s[tid]  = id;
    lens_s[tid] = a.len[id];
  }
  *reinterpret_cast<ushort4*>(&hs[0][tid * 4]) = make_ushort4(0, 0, 0, 0);
  __syncthreads();

  // stage neighbor lists (16 nodes x K ints)
  for (int i = tid; i < (16 << Klog); i += 512)
    nbr_s[i] = a.nbr[(size_t)ids_s[i >> Klog] * K + (i & (K - 1))];

  const int n  = lane & 15;                 // node column
  const int dq = lane >> 4;                 // k-quarter (B) / dim-quarter (D)
  const int d0 = wv * 16 + dq * 4;
  const int lenN = lens_s[n];
  const int kq = dq * 8;                    // this lane's k-offset within 32-slice

  int tmax = 1;
  #pragma unroll
  for (int b = 0; b < 16; b++) tmax = max(tmax, lens_s[b]);

  int offs[4];
  #pragma unroll
  for (int s = 0; s < 4; s++)
    offs[s] = (n * 128 + s * 32 + kq) ^ ((n & 7) << 3);
  const int hwo = (n * 128 + d0) ^ ((n & 7) << 3);

  bfrag Ag[4][8];
  #pragma unroll
  for (int g = 0; g < 4; g++) {
    #pragma unroll
    for (int s = 0; s < 8; s++)
      Ag[g][s] = *reinterpret_cast<const bfrag*>(
          a.Wg + (size_t)((((wv * 4 + g) * 8 + s) * 64 + lane) * 8));
  }

  f32x4 bias4[4];
  #pragma unroll
  for (int g = 0; g < 4; g++) {
    f32x4 bi = *reinterpret_cast<const f32x4*>(a.bih + g * 128 + d0);
    f32x4 bh = *reinterpret_cast<const f32x4*>(a.bhh + g * 128 + d0);
    const float sc = (g == 2) ? TL2E : -L2E;
    bias4[g] = (bi + bh) * sc;
  }

  __syncthreads();   // nbr_s + hs-zero visible

  // x B-frags for t=0, direct from global (lane reads node n's neighbor row)
  bfrag Bx[4];
  {
    const int idx = nbr_s[n << Klog];
    const uint16_t* src = a.hsrc + (size_t)idx * HD + kq;
    #pragma unroll
    for (int s = 0; s < 4; s++)
      Bx[s] = *reinterpret_cast<const bfrag*>(src + s * 32);
  }

  float cst[4] = {0.f, 0.f, 0.f, 0.f};
  uint2 hpk = {0u, 0u};

  for (int t = 0; t < tmax; ++t) {
    const int cur = t & 1, nxt = cur ^ 1;

    f32x4 C[4];
    #pragma unroll
    for (int g = 0; g < 4; g++) C[g] = bias4[g];

    // x-part: consume Bx (registers, no LDS)
    #pragma unroll
    for (int s = 0; s < 4; s++) {
      #pragma unroll
      for (int g = 0; g < 4; g++)
        C[g] = __builtin_amdgcn_mfma_f32_16x16x32_bf16(Ag[g][s], Bx[s], C[g], 0, 0, 0);
    }

    // reload Bx for t+1 (WAR after consumption; a full step of latency slack)
    {
      const int tn = (t + 1 < K) ? t + 1 : K - 1;
      const int idx = nbr_s[(n << Klog) + tn];
      const uint16_t* src = a.hsrc + (size_t)idx * HD + kq;
      #pragma unroll
      for (int s = 0; s < 4; s++)
        Bx[s] = *reinterpret_cast<const bfrag*>(src + s * 32);
    }

    // h-part: LDS exchange (the only cross-wave dependency)
    #pragma unroll
    for (int s = 0; s < 4; s++) {
      bfrag bh = *reinterpret_cast<const bfrag*>(&hs[cur][offs[s]]);
      #pragma unroll
      for (int g = 0; g < 4; g++)
        C[g] = __builtin_amdgcn_mfma_f32_16x16x32_bf16(Ag[g][s + 4], bh, C[g], 0, 0, 0);
    }

    if (t < lenN) {
      float hv[4];
      #pragma unroll
      for (int r = 0; r < 4; r++) {
        const float iv = __builtin_amdgcn_rcpf(1.0f + exp2ft(C[0][r]));
        const float fv = __builtin_amdgcn_rcpf(1.0f + exp2ft(C[1][r]));
        const float gv = 1.0f - 2.0f * __builtin_amdgcn_rcpf(1.0f + exp2ft(C[2][r]));
        const float ov = __builtin_amdgcn_rcpf(1.0f + exp2ft(C[3][r]));
        const float cn = fmaf(fv, cst[r], iv * gv);
        cst[r] = cn;
        const float th = 1.0f - 2.0f * __builtin_amdgcn_rcpf(1.0f + exp2ft(cn * TL2E));
        hv[r] = ov * th;
      }
      hpk.x = cvt_pk_bf16(hv[0], hv[1]);
      hpk.y = cvt_pk_bf16(hv[2], hv[3]);
    }

    *reinterpret_cast<uint2*>(&hs[nxt][hwo]) = hpk;
    __syncthreads();
  }

  const int fin = tmax & 1;

  // ---- epilogue: out = hdst@Wself^T + hn@Wneigh^T + b (+LN for items) ----
  bfrag Ae[8];
  #pragma unroll
  for (int s = 0; s < 8; s++)
    Ae[s] = *reinterpret_cast<const bfrag*>(
        a.We + (size_t)(((wv * 8 + s) * 64 + lane) * 8));

  // hdst B-frags direct from global
  bfrag Bd[4];
  {
    const uint16_t* src = a.hdst + (size_t)ids_s[n] * HD + kq;
    #pragma unroll
    for (int s = 0; s < 4; s++)
      Bd[s] = *reinterpret_cast<const bfrag*>(src + s * 32);
  }

  f32x4 O = *reinterpret_cast<const f32x4*>(a.bvec + d0);
  #pragma unroll
  for (int s = 0; s < 4; s++)
    O = __builtin_amdgcn_mfma_f32_16x16x32_bf16(Ae[s], Bd[s], O, 0, 0, 0);
  #pragma unroll
  for (int s = 0; s < 4; s++) {
    bfrag bh = *reinterpret_cast<const bfrag*>(&hs[fin][offs[s]]);
    O = __builtin_amdgcn_mfma_f32_16x16x32_bf16(Ae[s + 4], bh, O, 0, 0, 0);
  }

  const int oid = ids_s[n];
  if (!a.ln) {
    uint2 pk;
    pk.x = cvt_pk_bf16(O[0], O[1]);
    pk.y = cvt_pk_bf16(O[2], O[3]);
    *reinterpret_cast<uint2*>(a.outbf + (size_t)oid * HD + d0) = pk;
  } else {
    float s1 = O[0] + O[1] + O[2] + O[3];
    float s2 = O[0] * O[0] + O[1] * O[1] + O[2] * O[2] + O[3] * O[3];
    s1 += __shfl_xor(s1, 16); s2 += __shfl_xor(s2, 16);
    s1 += __shfl_xor(s1, 32); s2 += __shfl_xor(s2, 32);
    if (dq == 0) red[wv][n] = make_float2(s1, s2);
    __syncthreads();
    float m1 = 0.f, m2 = 0.f;
    #pragma unroll
    for (int w = 0; w < 8; w++) {
      float2 v = red[w][n];
      m1 += v.x; m2 += v.y;
    }
    const float mu   = m1 * (1.f / 128.f);
    const float var  = m2 * (1.f / 128.f) - mu * mu;
    const float istd = rsqrtf(var + 1e-5f);
    f32x4 gm = *reinterpret_cast<const f32x4*>(a.gamma + d0);
    f32x4 bt = *reinterpret_cast<const f32x4*>(a.beta + d0);
    float v[4];
    #pragma unroll
    for (int r = 0; r < 4; r++)
      v[r] = (O[r] - mu) * istd * gm[r] + bt[r];
    uint2 pk;
    pk.x = cvt_pk_bf16(v[0], v[1]);
    pk.y = cvt_pk_bf16(v[2], v[3]);
    *reinterpret_cast<uint2*>(a.outbf + (size_t)oid * HD + d0) = pk;
  }
}

// final Linear (no bias) + LeakyReLU, gathered by inv. Block = 16 outputs.
__global__ __launch_bounds__(512)
void final2_k(const uint16_t* __restrict__ hib, const int* __restrict__ inv,
              const uint16_t* __restrict__ fWf, float* __restrict__ out) {
  __shared__ int rid[16];
  const int tid = threadIdx.x, wv = tid >> 6, lane = tid & 63;
  const int i0 = blockIdx.x * 16;
  if (tid < 16) rid[tid] = inv[i0 + tid];
  __syncthreads();

  const int n = lane & 15, dq = lane >> 4;
  const int d0 = wv * 16 + dq * 4;
  bfrag Af[4];
  #pragma unroll
  for (int s = 0; s < 4; s++)
    Af[s] = *reinterpret_cast<const bfrag*>(fWf + (size_t)(((wv * 4 + s) * 64 + lane) * 8));

  bfrag Br[4];
  {
    const uint16_t* src = hib + (size_t)rid[n] * HD + dq * 8;
    #pragma unroll
    for (int s = 0; s < 4; s++)
      Br[s] = *reinterpret_cast<const bfrag*>(src + s * 32);
  }

  f32x4 O = {0.f, 0.f, 0.f, 0.f};
  #pragma unroll
  for (int s = 0; s < 4; s++)
    O = __builtin_amdgcn_mfma_f32_16x16x32_bf16(Af[s], Br[s], O, 0, 0, 0);
  float4 res;
  res.x = (O[0] > 0.f) ? O[0] : 0.01f * O[0];
  res.y = (O[1] > 0.f) ? O[1] : 0.01f * O[1];
  res.z = (O[2] > 0.f) ? O[2] : 0.01f * O[2];
  res.w = (O[3] > 0.f) ? O[3] : 0.01f * O[3];
  *reinterpret_cast<float4*>(out + (size_t)(i0 + n) * HD + d0) = res;
}

} // namespace

extern "C" void kernel_launch(void* const* d_in, const int* in_sizes, int n_in,
                              void* d_out, int out_size, void* d_ws, size_t ws_size,
                              hipStream_t stream) {
  (void)in_sizes; (void)n_in; (void)out_size; (void)ws_size;

  const int*   items      = (const int*)d_in[0];
  const int*   nbr_item   = (const int*)d_in[1];
  const int*   len_tag    = (const int*)d_in[2];
  const int*   nbr_tag    = (const int*)d_in[3];
  const int*   len_item   = (const int*)d_in[4];
  const float* item_table = (const float*)d_in[5];
  const float* tag_table  = (const float*)d_in[6];
  const float* Wih_as   = (const float*)d_in[7];
  const float* Whh_as   = (const float*)d_in[8];
  const float* bih_as   = (const float*)d_in[9];
  const float* bhh_as   = (const float*)d_in[10];
  const float* Wself_as  = (const float*)d_in[11];
  const float* Wneigh_as = (const float*)d_in[12];
  const float* b_as      = (const float*)d_in[13];
  const float* Wih_ras   = (const float*)d_in[14];
  const float* Whh_ras   = (const float*)d_in[15];
  const float* bih_ras   = (const float*)d_in[16];
  const float* bhh_ras   = (const float*)d_in[17];
  const float* Wself_ras  = (const float*)d_in[18];
  const float* Wneigh_ras = (const float*)d_in[19];
  const float* b_ras      = (const float*)d_in[20];
  const float* ln_gamma = (const float*)d_in[21];
  const float* ln_beta  = (const float*)d_in[22];
  const float* W_final  = (const float*)d_in[23];
  float* out = (float*)d_out;

  char* p = (char*)d_ws;
  auto take = [&](size_t bytes) -> char* {
    char* r = p;
    p += (bytes + 255) & ~(size_t)255;
    return r;
  };
  int* present = (int*)take((size_t)VOCAB * sizeof(int));
  int* rank    = (int*)take((size_t)(VOCAB + 1) * sizeof(int));
  int* invp    = (int*)take((size_t)N_ITEMS * sizeof(int));
  int* partial = (int*)take(64 * sizeof(int));
  uint16_t* hti0 = (uint16_t*)take((size_t)N_ITEMS * HD * 2);
  uint16_t* htiA = (uint16_t*)take((size_t)N_ITEMS * HD * 2);
  uint16_t* htiB = (uint16_t*)take((size_t)N_ITEMS * HD * 2);
  uint16_t* htt0 = (uint16_t*)take((size_t)N_TAGS * HD * 2);
  uint16_t* httA = (uint16_t*)take((size_t)N_TAGS * HD * 2);
  uint16_t* httB = (uint16_t*)take((size_t)N_TAGS * HD * 2);
  uint16_t* WgA = (uint16_t*)take((size_t)GWSZ * 2);
  uint16_t* WgR = (uint16_t*)take((size_t)GWSZ * 2);
  uint16_t* WeA = (uint16_t*)take((size_t)EWSZ * 2);
  uint16_t* WeR = (uint16_t*)take((size_t)EWSZ * 2);
  uint16_t* fWf = (uint16_t*)take((size_t)FWSZ * 2);
  int* hists = (int*)take((size_t)(KTAG + 1 + KITEM + 1) * sizeof(int));
  int* hist_tag  = hists;
  int* hist_item = hists + KTAG + 1;
  int* base_tag  = (int*)take((size_t)(KTAG + 1) * sizeof(int));
  int* base_item = (int*)take((size_t)(KITEM + 1) * sizeof(int));
  int* ord_tag   = (int*)take((size_t)N_TAGS * sizeof(int));
  int* ord_item  = (int*)take((size_t)N_ITEMS * sizeof(int));

  const int NHIST = KTAG + 1 + KITEM + 1;
  const int NPREP = NBPI + NCONV;

  zero_k<<<(VOCAB + NHIST + 255) / 256, 256, 0, stream>>>(present, hists, NHIST);
  markhist2_k<<<(N_ITEMS + 255) / 256, 256, 0, stream>>>(
      items, present, len_tag, len_item, hist_tag, hist_item);
  scanA_k<<<NSCAN, 256, 0, stream>>>(present, partial, hist_tag, base_tag,
                                     hist_item, base_item);
  scanC_k<<<NSCAN, 256, 0, stream>>>(present, partial, rank);
  scatter2_k<<<(N_ITEMS + 255) / 256, 256, 0, stream>>>(
      len_tag, len_item, base_tag, base_item, ord_tag, ord_item);
  prep_k<<<(NPREP + 255) / 256, 256, 0, stream>>>(
      present, rank, items, item_table, tag_table, hti0, htt0, invp,
      Wih_as, Whh_as, Wih_ras, Whh_ras, Wself_as, Wneigh_as, Wself_ras, Wneigh_ras,
      W_final, WgA, WgR, WeA, WeR, fWf);

  const uint16_t* hi_cur = hti0; uint16_t* hi_nxt = htiA;
  const uint16_t* ht_cur = htt0; uint16_t* ht_nxt = httA;

  for (int l = 0; l < NLAYER; ++l) {
    ConvArgs3 ta, ia;
    ta.hsrc = hi_cur; ta.hdst = ht_cur;
    ta.nbr = nbr_item; ta.len = len_tag; ta.ord = ord_tag;
    ta.Wg = WgA + (size_t)l * 131072; ta.We = WeA + (size_t)l * 32768;
    ta.bih = bih_as + (size_t)l * 512; ta.bhh = bhh_as + (size_t)l * 512;
    ta.bvec = b_as + (size_t)l * HD;
    ta.gamma = nullptr; ta.beta = nullptr;
    ta.outbf = ht_nxt; ta.K = KTAG; ta.Klog = 5; ta.ln = 0; ta.nblk = N_TAGS / 16;

    ia.hsrc = ht_cur; ia.hdst = hi_cur;
    ia.nbr = nbr_tag; ia.len = len_item; ia.ord = ord_item;
    ia.Wg = WgR + (size_t)l * 131072; ia.We = WeR + (size_t)l * 32768;
    ia.bih = bih_ras + (size_t)l * 512; ia.bhh = bhh_ras + (size_t)l * 512;
    ia.bvec = b_ras + (size_t)l * HD;
    ia.gamma = ln_gamma + (size_t)l * HD; ia.beta = ln_beta + (size_t)l * HD;
    ia.outbf = hi_nxt; ia.K = KITEM; ia.Klog = 3; ia.ln = 1; ia.nblk = N_ITEMS / 16;

    layer12_k<<<ta.nblk + ia.nblk, 512, 0, stream>>>(ta, ia);

    hi_cur = hi_nxt; hi_nxt = (hi_cur == htiA) ? htiB : htiA;
    ht_cur = ht_nxt; ht_nxt = (ht_cur == httA) ? httB : httA;
  }

  final2_k<<<N_ITEMS / 16, 512, 0, stream>>>(hi_cur, invp, fWf, out);
}